// Round 5
// baseline (152.013 us; speedup 1.0000x reference)
//
#include <hip/hip_runtime.h>
#include <hip/hip_bf16.h>
#include <stdint.h>

// Problem constants (fixed by setup_inputs)
#define M_N  16384   // batch rows
#define K_C  2048    // centers
#define DIM  512     // feature dim
#define NCLS 10      // classes
#define NBN  (K_C / 128)   // 16 center-blocks -> partial slices

typedef unsigned short u16;
typedef float  f32x4  __attribute__((ext_vector_type(4)));
typedef __bf16 bf16x8 __attribute__((ext_vector_type(8)));

// ---- helpers -------------------------------------------------------------

__device__ __forceinline__ void async_ld16(const void* g, void* l) {
  // global -> LDS direct DMA, 16 bytes per lane. LDS dest is wave-uniform
  // base + lane*16 (lds off linear in tid) -- swizzle must be on the SOURCE.
  __builtin_amdgcn_global_load_lds(
      (const __attribute__((address_space(1))) void*)g,
      (__attribute__((address_space(3))) void*)l,
      16, 0, 0);
}

__device__ __forceinline__ u16 f2bf_rne(float f) {
  uint32_t u = __float_as_uint(f);
  u += 0x7FFFu + ((u >> 16) & 1u);
  return (u16)(u >> 16);
}

// ---- kernel 1: one prep kernel for batches + centers + W -----------------
// blocks [0, M_N)            : batches row conversion + x2
// blocks [M_N, M_N+K_C)      : centers row conversion + c2
// blocks [M_N+K_C, +128)     : W fp32 [10][2048] -> bf16 [16][2048] (pad 0)

__device__ __forceinline__ void conv_row(const float4* __restrict__ src,
                                         ushort4* __restrict__ dst,
                                         float* __restrict__ sq,
                                         int row, int t) {
  float4 v = src[(size_t)row * 128 + t];
  float ss = v.x * v.x + v.y * v.y + v.z * v.z + v.w * v.w;
  ushort4 o;
  o.x = f2bf_rne(v.x); o.y = f2bf_rne(v.y);
  o.z = f2bf_rne(v.z); o.w = f2bf_rne(v.w);
  dst[(size_t)row * 128 + t] = o;
  ss += __shfl_down(ss, 32);
  ss += __shfl_down(ss, 16);
  ss += __shfl_down(ss, 8);
  ss += __shfl_down(ss, 4);
  ss += __shfl_down(ss, 2);
  ss += __shfl_down(ss, 1);
  __shared__ float part[2];
  if ((t & 63) == 0) part[t >> 6] = ss;
  __syncthreads();
  if (t == 0) sq[row] = part[0] + part[1];
}

__global__ void prep(const float4* __restrict__ batches,
                     const float4* __restrict__ centers,
                     const float* __restrict__ W,
                     ushort4* __restrict__ Abf, ushort4* __restrict__ Bbf,
                     float* __restrict__ x2, float* __restrict__ c2,
                     u16* __restrict__ Wbf) {
  int b = blockIdx.x, t = threadIdx.x;   // 128 threads
  if (b < M_N) {
    conv_row(batches, Abf, x2, b, t);
  } else if (b < M_N + K_C) {
    conv_row(centers, Bbf, c2, b - M_N, t);
  } else {
    int wb = b - (M_N + K_C);            // 128 blocks x 256 elems
#pragma unroll
    for (int i = 0; i < 2; ++i) {
      int idx = wb * 256 + i * 128 + t;  // < 16*2048
      int n = idx >> 11, k = idx & 2047;
      Wbf[idx] = (n < NCLS) ? f2bf_rne(W[n * K_C + k]) : (u16)0;
    }
  }
}

// ---- kernel 2: fused xc-GEMM -> radial -> MFMA (radial @ W^T) ------------
// grid = 2048 blocks, 256 threads (4 waves, 2x2 of 64x64). BK=64.
// XCD swizzle: bid = g*8+r -> bm = r*16 + (g&15), bn = g>>4, so each XCD
// (~bid%8) covers one 16-row bm slice x all bn: A-slice 2MB + B 2MB fit L2.
// Stage-1 computes D[center][batch]; radial round-trips LDS row-major
// swizzled; stage-2 = MFMA against W bf16 [16][2048] (rows 10..15 zero).

__global__ __launch_bounds__(256, 4) void rbf_main(
    const u16* __restrict__ A,      // bf16 bits [M_N][DIM]  (batches)
    const u16* __restrict__ B,      // bf16 bits [K_C][DIM]  (centers)
    const float* __restrict__ x2,   // [M_N]
    const float* __restrict__ c2,   // [K_C]
    const float* __restrict__ beta, // [K_C]
    const u16* __restrict__ Wbf,    // bf16 bits [16][K_C]
    float* __restrict__ partial) {  // [NBN][M_N][NCLS]
  constexpr int BK = 64;
  __shared__ alignas(16) unsigned char smem[32768];
  u16* As = (u16*)smem;            // batches [128][64] swizzled
  u16* Bs = (u16*)(smem + 16384);  // centers [128][64] swizzled
  u16* Rt = (u16*)smem;            // radial row-major [128][128] swizzled

  const int tid  = threadIdx.x;
  const int lane = tid & 63;
  const int wid  = tid >> 6;
  const int bid = blockIdx.x;
  const int g = bid >> 3, r8 = bid & 7;
  const int bm = r8 * 16 + (g & 15);
  const int bn = g >> 4;
  const int row0 = bm * 128, col0 = bn * 128;
  const int wrC = (wid >> 1) * 64;   // wave CENTER offset in tile
  const int wcB = (wid & 1) * 64;    // wave BATCH offset in tile

  f32x4 acc[4][4] = {};   // acc[mi = center strip][ni = batch strip]

  // staging: thread t -> LDS slot (row=t>>3, s=t&7); loads global chunk
  // g = s ^ (row&7) so LDS[r][c^(r&7)] = global (r, chunk c).
  const int srow = tid >> 3;
  const int scol = ((tid & 7) ^ (srow & 7)) * 8;
  const u16* aG = A + (size_t)(row0 + srow) * DIM + scol;
  const u16* bG = B + (size_t)(col0 + srow) * DIM + scol;
  u16* aL = As + tid * 8;
  u16* bL = Bs + tid * 8;

  const int frow = lane & 15;      // MFMA operand row (m or n)
  const int fq   = lane >> 4;      // k-quarter
  const int fsw  = frow & 7;       // swizzle key

  for (int k0 = 0; k0 < DIM; k0 += BK) {
    __syncthreads();  // previous iter's ds_reads done before overwrite
#pragma unroll
    for (int i = 0; i < 4; ++i) {
      async_ld16(aG + k0 + i * 32 * DIM, aL + i * 2048);
      async_ld16(bG + k0 + i * 32 * DIM, bL + i * 2048);
    }
    __syncthreads();  // vmcnt drained before s_barrier -> tiles ready

#pragma unroll
    for (int kh = 0; kh < 2; ++kh) {
      const int slot = ((kh << 2) | fq) ^ fsw;   // swizzled 16B chunk
      bf16x8 cf[4], bfr[4];
#pragma unroll
      for (int mi = 0; mi < 4; ++mi)   // centers = FIRST operand
        cf[mi] = *(const bf16x8*)(Bs + (wrC + mi * 16 + frow) * BK + slot * 8);
#pragma unroll
      for (int ni = 0; ni < 4; ++ni)   // batches = SECOND operand
        bfr[ni] = *(const bf16x8*)(As + (wcB + ni * 16 + frow) * BK + slot * 8);
#pragma unroll
      for (int mi = 0; mi < 4; ++mi)
#pragma unroll
        for (int ni = 0; ni < 4; ++ni)
          acc[mi][ni] = __builtin_amdgcn_mfma_f32_16x16x32_bf16(
              cf[mi], bfr[ni], acc[mi][ni], 0, 0, 0);
    }
  }

  // ---- epilogue scalars ----
  // D layout: col(lane&15)=batch within 16-strip, row(q*4+reg)=center.
  const int cls = lane & 15, q = lane >> 4;
  float4 c2q[4], btq[4];
#pragma unroll
  for (int mi = 0; mi < 4; ++mi) {
    int base = col0 + wrC + mi * 16 + q * 4;   // 4 consecutive centers
    c2q[mi] = *(const float4*)(c2 + base);
    btq[mi] = *(const float4*)(beta + base);
  }
  float x2v[4];
#pragma unroll
  for (int ni = 0; ni < 4; ++ni)
    x2v[ni] = x2[row0 + wcB + ni * 16 + cls];

  __syncthreads();  // K-loop LDS use finished; smem becomes Rt

  // Rt[br][cc] stored at br*128 + (cc ^ ((br&15)<<3))
  union Pack { u16 h[4]; uint2 v; };
#pragma unroll
  for (int mi = 0; mi < 4; ++mi) {
#pragma unroll
    for (int ni = 0; ni < 4; ++ni) {
      Pack pk;
#pragma unroll
      for (int r = 0; r < 4; ++r) {
        float xc = acc[mi][ni][r];
        float d2 = fmaxf(x2v[ni] + c2q[mi][r] - 2.0f * xc, 0.0f);
        float radial = __expf(-btq[mi][r] * sqrtf(d2));
        pk.h[r] = f2bf_rne(radial);
      }
      int br  = wcB + ni * 16 + cls;           // batch row in tile
      int cc0 = wrC + mi * 16 + q * 4;         // 4 consecutive centers
      *(uint2*)(Rt + br * 128 + (cc0 ^ ((br & 15) << 3))) = pk.v;
    }
  }
  __syncthreads();

  // ---- W fragments loaded HERE (acc dead -> lower peak regs) ----
  bf16x8 wfr[4];
#pragma unroll
  for (int t = 0; t < 4; ++t)
    wfr[t] = *(const bf16x8*)(Wbf + (size_t)cls * K_C + col0 + t * 32 + q * 8);

  // ---- stage 2: out2[128 x 16] = radial[128 x 128] @ W^T via MFMA ----
  f32x4 acc2[2] = {};
#pragma unroll
  for (int s2 = 0; s2 < 2; ++s2) {
    const int br = (wid * 2 + s2) * 16 + cls;
    const u16* rrow = Rt + br * 128;
    const int sw = cls << 3;                   // (br&15)<<3 == cls<<3
#pragma unroll
    for (int t = 0; t < 4; ++t) {
      bf16x8 ra = *(const bf16x8*)(rrow + ((t * 32 + q * 8) ^ sw));
      acc2[s2] = __builtin_amdgcn_mfma_f32_16x16x32_bf16(
          ra, wfr[t], acc2[s2], 0, 0, 0);
    }
  }

  // store: D2 col(lane&15)=class, row(q*4+r)=batch row within strip.
  // partial layout [bn][M_N][10]; cols 10..15 are zeros -> skipped.
  if (cls < NCLS) {
#pragma unroll
    for (int s2 = 0; s2 < 2; ++s2)
#pragma unroll
      for (int r = 0; r < 4; ++r) {
        int gr = row0 + (wid * 2 + s2) * 16 + q * 4 + r;
        partial[(size_t)bn * (M_N * NCLS) + (size_t)gr * NCLS + cls] =
            acc2[s2][r];
      }
  }
}

// ---- kernel 3: out[i][j] = b[j] + sum_bn partial[bn][i][j] ---------------
// fully coalesced: 16 contiguous streams

__global__ void reduce_out(const float* __restrict__ partial,
                           const float* __restrict__ b,
                           float* __restrict__ out) {
  int idx = blockIdx.x * 256 + threadIdx.x;
  if (idx >= M_N * NCLS) return;
  int j = idx % NCLS;
  float s = b[j];
#pragma unroll
  for (int bn = 0; bn < NBN; ++bn)
    s += partial[(size_t)bn * (M_N * NCLS) + idx];
  out[idx] = s;
}

// ---- launch --------------------------------------------------------------

extern "C" void kernel_launch(void* const* d_in, const int* in_sizes, int n_in,
                              void* d_out, int out_size, void* d_ws, size_t ws_size,
                              hipStream_t stream) {
  const float* batches = (const float*)d_in[0];  // [16384,512]
  const float* centers = (const float*)d_in[1];  // [2048,512]
  const float* beta    = (const float*)d_in[2];  // [1,2048]
  const float* W       = (const float*)d_in[3];  // [10,2048]
  const float* bias    = (const float*)d_in[4];  // [10]
  float* out = (float*)d_out;                    // [16384,10]

  char* ws = (char*)d_ws;
  u16*  Abf = (u16*)ws;                                   // 16 MiB
  u16*  Bbf = (u16*)(ws + (size_t)M_N * DIM * 2);         // 2 MiB
  float* x2 = (float*)(ws + (size_t)(M_N + K_C) * DIM * 2);
  float* c2 = x2 + M_N;
  u16*  Wbf = (u16*)(c2 + K_C);                           // 64 KiB
  float* partial = (float*)((char*)Wbf + 16 * K_C * 2);   // 10.5 MiB

  prep<<<dim3(M_N + K_C + 128), dim3(128), 0, stream>>>(
      (const float4*)batches, (const float4*)centers, W,
      (ushort4*)Abf, (ushort4*)Bbf, x2, c2, Wbf);
  rbf_main<<<dim3(NBN * (M_N / 128)), dim3(256), 0, stream>>>(
      Abf, Bbf, x2, c2, beta, Wbf, partial);
  reduce_out<<<dim3((M_N * NCLS + 255) / 256), dim3(256), 0, stream>>>(
      partial, bias, out);
}

// Round 6
// 148.456 us; speedup vs baseline: 1.0240x; 1.0240x over previous
//
#include <hip/hip_runtime.h>
#include <hip/hip_bf16.h>
#include <stdint.h>

// Problem constants (fixed by setup_inputs)
#define M_N  16384   // batch rows
#define K_C  2048    // centers
#define DIM  512     // feature dim
#define NCLS 10      // classes
#define NBN  (K_C / 128)   // 16 center-blocks -> partial slices

typedef unsigned short u16;
typedef float  f32x4  __attribute__((ext_vector_type(4)));
typedef __bf16 bf16x8 __attribute__((ext_vector_type(8)));

// ---- helpers -------------------------------------------------------------

__device__ __forceinline__ void async_ld16(const void* g, void* l) {
  // global -> LDS direct DMA, 16 bytes per lane. LDS dest is wave-uniform
  // base + lane*16 (lds off linear in tid) -- swizzle must be on the SOURCE.
  __builtin_amdgcn_global_load_lds(
      (const __attribute__((address_space(1))) void*)g,
      (__attribute__((address_space(3))) void*)l,
      16, 0, 0);
}

__device__ __forceinline__ u16 f2bf_rne(float f) {
  uint32_t u = __float_as_uint(f);
  u += 0x7FFFu + ((u >> 16) & 1u);
  return (u16)(u >> 16);
}

// ---- kernel 1: one prep kernel for batches + centers + W -----------------
// 256 threads. blocks [0, (M_N+K_C)/2): two data rows per block.
// last 32 blocks: W fp32 [10][2048] -> bf16 [16][2048] (rows 10..15 = 0).

#define NPREP ((M_N + K_C) / 2)

__global__ __launch_bounds__(256) void prep(
    const float4* __restrict__ batches, const float4* __restrict__ centers,
    const float* __restrict__ W,
    ushort4* __restrict__ Abf, ushort4* __restrict__ Bbf,
    float* __restrict__ x2, float* __restrict__ c2, u16* __restrict__ Wbf) {
  int b = blockIdx.x, t = threadIdx.x;
  if (b < NPREP) {
    int rp = b * 2 + (t >> 7);          // row index (pair)
    int col = t & 127;
    const float4* src; ushort4* dst; float* sq; int row;
    if (rp < M_N) { src = batches; dst = Abf; sq = x2; row = rp; }
    else          { src = centers; dst = Bbf; sq = c2; row = rp - M_N; }
    float4 v = src[(size_t)row * 128 + col];
    float ss = v.x * v.x + v.y * v.y + v.z * v.z + v.w * v.w;
    ushort4 o;
    o.x = f2bf_rne(v.x); o.y = f2bf_rne(v.y);
    o.z = f2bf_rne(v.z); o.w = f2bf_rne(v.w);
    dst[(size_t)row * 128 + col] = o;
    ss += __shfl_down(ss, 32);
    ss += __shfl_down(ss, 16);
    ss += __shfl_down(ss, 8);
    ss += __shfl_down(ss, 4);
    ss += __shfl_down(ss, 2);
    ss += __shfl_down(ss, 1);
    __shared__ float part[4];
    if ((t & 63) == 0) part[t >> 6] = ss;
    __syncthreads();
    if (t == 0) sq[row] = part[0] + part[1];
    if (t == 128) sq[row] = part[2] + part[3];
  } else {
    int wb = b - NPREP;                 // 32 blocks x 1024 elems
#pragma unroll
    for (int i = 0; i < 4; ++i) {
      int idx = wb * 1024 + i * 256 + t;  // < 16*2048
      int n = idx >> 11, k = idx & 2047;
      Wbf[idx] = (n < NCLS) ? f2bf_rne(W[n * K_C + k]) : (u16)0;
    }
  }
}

// ---- kernel 2: fused xc-GEMM -> radial -> MFMA (radial @ W^T) ------------
// grid = 2048 blocks, 256 threads (4 waves, 2x2 of 64x64). BK=64.
// XCD swizzle: bid = g*8+r -> bm = r*16 + (g&15), bn = g>>4: each XCD owns a
// 2 MB A-slice + 2 MB B, fits its L2 (measured FETCH 85->53 MB).
// Stage-1 computes D[center][batch]; radial round-trips LDS row-major
// swizzled; stage-2 = MFMA against W bf16 [16][2048] (rows 10..15 zero).
// partial layout [M_N][NBN][16]: 16 lanes store 16 consecutive floats =
// full 64 B sectors (R5's [bn][M][10] 40 B fragments cost +32 MB HBM RMW).

__global__ __launch_bounds__(256, 4) void rbf_main(
    const u16* __restrict__ A,      // bf16 bits [M_N][DIM]  (batches)
    const u16* __restrict__ B,      // bf16 bits [K_C][DIM]  (centers)
    const float* __restrict__ x2,   // [M_N]
    const float* __restrict__ c2,   // [K_C]
    const float* __restrict__ beta, // [K_C]
    const u16* __restrict__ Wbf,    // bf16 bits [16][K_C]
    float* __restrict__ partial) {  // [M_N][NBN][16]
  constexpr int BK = 64;
  __shared__ alignas(16) unsigned char smem[32768];
  u16* As = (u16*)smem;            // batches [128][64] swizzled
  u16* Bs = (u16*)(smem + 16384);  // centers [128][64] swizzled
  u16* Rt = (u16*)smem;            // radial row-major [128][128] swizzled

  const int tid  = threadIdx.x;
  const int lane = tid & 63;
  const int wid  = tid >> 6;
  const int bid = blockIdx.x;
  const int g = bid >> 3, r8 = bid & 7;
  const int bm = r8 * 16 + (g & 15);
  const int bn = g >> 4;
  const int row0 = bm * 128, col0 = bn * 128;
  const int wrC = (wid >> 1) * 64;   // wave CENTER offset in tile
  const int wcB = (wid & 1) * 64;    // wave BATCH offset in tile

  f32x4 acc[4][4] = {};   // acc[mi = center strip][ni = batch strip]

  // staging: thread t -> LDS slot (row=t>>3, s=t&7); loads global chunk
  // g = s ^ (row&7) so LDS[r][c^(r&7)] = global (r, chunk c).
  const int srow = tid >> 3;
  const int scol = ((tid & 7) ^ (srow & 7)) * 8;
  const u16* aG = A + (size_t)(row0 + srow) * DIM + scol;
  const u16* bG = B + (size_t)(col0 + srow) * DIM + scol;
  u16* aL = As + tid * 8;
  u16* bL = Bs + tid * 8;

  const int frow = lane & 15;      // MFMA operand row (m or n)
  const int fq   = lane >> 4;      // k-quarter
  const int fsw  = frow & 7;       // swizzle key

  for (int k0 = 0; k0 < DIM; k0 += BK) {
    __syncthreads();  // previous iter's ds_reads done before overwrite
#pragma unroll
    for (int i = 0; i < 4; ++i) {
      async_ld16(aG + k0 + i * 32 * DIM, aL + i * 2048);
      async_ld16(bG + k0 + i * 32 * DIM, bL + i * 2048);
    }
    __syncthreads();  // vmcnt drained before s_barrier -> tiles ready

#pragma unroll
    for (int kh = 0; kh < 2; ++kh) {
      const int slot = ((kh << 2) | fq) ^ fsw;   // swizzled 16B chunk
      bf16x8 cf[4], bfr[4];
#pragma unroll
      for (int mi = 0; mi < 4; ++mi)   // centers = FIRST operand
        cf[mi] = *(const bf16x8*)(Bs + (wrC + mi * 16 + frow) * BK + slot * 8);
#pragma unroll
      for (int ni = 0; ni < 4; ++ni)   // batches = SECOND operand
        bfr[ni] = *(const bf16x8*)(As + (wcB + ni * 16 + frow) * BK + slot * 8);
#pragma unroll
      for (int mi = 0; mi < 4; ++mi)
#pragma unroll
        for (int ni = 0; ni < 4; ++ni)
          acc[mi][ni] = __builtin_amdgcn_mfma_f32_16x16x32_bf16(
              cf[mi], bfr[ni], acc[mi][ni], 0, 0, 0);
    }
  }

  // ---- epilogue scalars ----
  // D layout: col(lane&15)=batch within 16-strip, row(q*4+reg)=center.
  const int cls = lane & 15, q = lane >> 4;
  float4 c2q[4], btq[4];
#pragma unroll
  for (int mi = 0; mi < 4; ++mi) {
    int base = col0 + wrC + mi * 16 + q * 4;   // 4 consecutive centers
    c2q[mi] = *(const float4*)(c2 + base);
    btq[mi] = *(const float4*)(beta + base);
  }
  float x2v[4];
#pragma unroll
  for (int ni = 0; ni < 4; ++ni)
    x2v[ni] = x2[row0 + wcB + ni * 16 + cls];

  __syncthreads();  // K-loop LDS use finished; smem becomes Rt

  // Rt[br][cc] stored at br*128 + (cc ^ ((br&15)<<3))
  union Pack { u16 h[4]; uint2 v; };
#pragma unroll
  for (int mi = 0; mi < 4; ++mi) {
#pragma unroll
    for (int ni = 0; ni < 4; ++ni) {
      Pack pk;
#pragma unroll
      for (int r = 0; r < 4; ++r) {
        float xc = acc[mi][ni][r];
        float d2 = fmaxf(x2v[ni] + c2q[mi][r] - 2.0f * xc, 0.0f);
        float radial = __expf(-btq[mi][r] * sqrtf(d2));
        pk.h[r] = f2bf_rne(radial);
      }
      int br  = wcB + ni * 16 + cls;           // batch row in tile
      int cc0 = wrC + mi * 16 + q * 4;         // 4 consecutive centers
      *(uint2*)(Rt + br * 128 + (cc0 ^ ((br & 15) << 3))) = pk.v;
    }
  }
  __syncthreads();

  // ---- W fragments (acc dead -> lower peak regs) ----
  bf16x8 wfr[4];
#pragma unroll
  for (int t = 0; t < 4; ++t)
    wfr[t] = *(const bf16x8*)(Wbf + (size_t)cls * K_C + col0 + t * 32 + q * 8);

  // ---- stage 2: out2[128 x 16] = radial[128 x 128] @ W^T via MFMA ----
  f32x4 acc2[2] = {};
#pragma unroll
  for (int s2 = 0; s2 < 2; ++s2) {
    const int br = (wid * 2 + s2) * 16 + cls;
    const u16* rrow = Rt + br * 128;
    const int sw = cls << 3;                   // (br&15)<<3 == cls<<3
#pragma unroll
    for (int t = 0; t < 4; ++t) {
      bf16x8 ra = *(const bf16x8*)(rrow + ((t * 32 + q * 8) ^ sw));
      acc2[s2] = __builtin_amdgcn_mfma_f32_16x16x32_bf16(
          ra, wfr[t], acc2[s2], 0, 0, 0);
    }
  }

  // store: D2 col(lane&15)=class, row(q*4+r)=batch row within strip.
  // all 16 cols stored (10..15 exact zeros): 16 lanes x 4 B = full 64 B.
#pragma unroll
  for (int s2 = 0; s2 < 2; ++s2)
#pragma unroll
    for (int r = 0; r < 4; ++r) {
      int gr = row0 + (wid * 2 + s2) * 16 + q * 4 + r;
      partial[(size_t)gr * (NBN * 16) + bn * 16 + cls] = acc2[s2][r];
    }
}

// ---- kernel 3: one wave per row: out[i][:] = b + sum_bn partial[i][bn][:] -
// lane l reads float4 #l of the row's 1 KB partial strip (fully coalesced),
// butterfly-sums over bn (lanes stride 4), lanes 0..2 write the 10 outputs.

__global__ __launch_bounds__(256) void reduce_out(
    const float* __restrict__ partial, const float* __restrict__ b,
    float* __restrict__ out) {
  int lane = threadIdx.x & 63;
  int row = blockIdx.x * 4 + (threadIdx.x >> 6);
  float4 v = ((const float4*)(partial + (size_t)row * (NBN * 16)))[lane];
  // sum over the 16 bn-groups: lanes with equal (lane&3)
#pragma unroll
  for (int m = 4; m < 64; m <<= 1) {
    v.x += __shfl_xor(v.x, m);
    v.y += __shfl_xor(v.y, m);
    v.z += __shfl_xor(v.z, m);
    v.w += __shfl_xor(v.w, m);
  }
  int c = lane & 3;           // class quad id
  if (lane < 2) {             // lanes 0,1: classes 0-3 / 4-7
    float4 bq = ((const float4*)b)[c];
    v.x += bq.x; v.y += bq.y; v.z += bq.z; v.w += bq.w;
    ((float2*)(out + (size_t)row * NCLS + c * 4))[0] = {v.x, v.y};
    ((float2*)(out + (size_t)row * NCLS + c * 4 + 2))[0] = {v.z, v.w};
  } else if (lane == 2) {     // classes 8,9
    float2 o = {v.x + b[8], v.y + b[9]};
    *(float2*)(out + (size_t)row * NCLS + 8) = o;
  }
}

// ---- launch --------------------------------------------------------------

extern "C" void kernel_launch(void* const* d_in, const int* in_sizes, int n_in,
                              void* d_out, int out_size, void* d_ws, size_t ws_size,
                              hipStream_t stream) {
  const float* batches = (const float*)d_in[0];  // [16384,512]
  const float* centers = (const float*)d_in[1];  // [2048,512]
  const float* beta    = (const float*)d_in[2];  // [1,2048]
  const float* W       = (const float*)d_in[3];  // [10,2048]
  const float* bias    = (const float*)d_in[4];  // [10]
  float* out = (float*)d_out;                    // [16384,10]

  char* ws = (char*)d_ws;
  u16*  Abf = (u16*)ws;                                   // 16 MiB
  u16*  Bbf = (u16*)(ws + (size_t)M_N * DIM * 2);         // 2 MiB
  float* x2 = (float*)(ws + (size_t)(M_N + K_C) * DIM * 2);
  float* c2 = x2 + M_N;
  u16*  Wbf = (u16*)(c2 + K_C);                           // 64 KiB
  float* partial = (float*)((char*)Wbf + 16 * K_C * 2);   // 16.8 MiB

  prep<<<dim3(NPREP + 32), dim3(256), 0, stream>>>(
      (const float4*)batches, (const float4*)centers, W,
      (ushort4*)Abf, (ushort4*)Bbf, x2, c2, Wbf);
  rbf_main<<<dim3(NBN * (M_N / 128)), dim3(256), 0, stream>>>(
      Abf, Bbf, x2, c2, beta, Wbf, partial);
  reduce_out<<<dim3(M_N / 4), dim3(256), 0, stream>>>(partial, bias, out);
}